// Round 10
// baseline (1038.499 us; speedup 1.0000x reference)
//
#include <hip/hip_runtime.h>

// Multi-head VQ: inputs (16,2048,1024) f32, embeddings (4,64,256) f32.
// Out flat f32: quantized_st[33554432] | loss[1] | indices[131072 as float].
// Block = 512 thr = 2 token-groups x 4 code-slabs, one head; full head
// codebook (64 KB) in LDS; e-rows read uniform-address (broadcast).
// R10 = R8 except __launch_bounds__(512, 2): the allocator caps VGPR at
// ~256/min_waves (R3/R5/R6/R7/R9 evidence: 2->128, 4->64, 8->32). R8's
// (512,4) cap of 64 < ~100 demand caused 9.9 GB scratch spill; (512,2)
// gives cap 128 >= demand. Runtime residency is NOT capped by the bound
// (R3 evidence); LDS 68 KB -> 2 blocks/CU -> 4 waves/SIMD.
// quantized_st written as q directly (|x+(q-x)-q| ~1e-6 << 1.26 thr);
// loss = min distance (== ||q-x||^2 within ~1e-6 rel).

#define HH   4
#define KK   64
#define HD   256
#define DD   1024
#define NTOK 32768
#define NDQ  33554432ull
#define NPART 2048   // 1024 blocks * 2 token-groups

__global__ void vq_cbq(const float* __restrict__ emb, float* __restrict__ cbq)
{
    const int t = threadIdx.x;               // one per (h,k)
    const float* e = emb + (size_t)t * HD;
    float s = 0.f;
    {
        #pragma clang fp contract(off)
        for (int d = 0; d < HD; ++d) {
            float p = e[d] * e[d];
            s = s + p;
        }
    }
    cbq[t] = s;
}

__global__ __launch_bounds__(512, 2) void vq_main(
    const float* __restrict__ x, const float* __restrict__ emb,
    const float* __restrict__ cbq, float* __restrict__ out,
    double* __restrict__ partial)
{
    __shared__ __align__(16) float e_lds[KK * HD];   // 64 KB, rows contiguous
    __shared__ float vals[8][64];
    __shared__ int   idxs[8][64];
    __shared__ int   fidx[128];

    const int h   = blockIdx.y;
    const int tid = threadIdx.x;
    const float* __restrict__ eh = emb + (size_t)h * (KK * HD);

    // Stage full head codebook into LDS (float4, coalesced).
    for (int i = tid; i < KK * HD / 4; i += 512)
        ((float4*)e_lds)[i] = ((const float4*)eh)[i];
    __syncthreads();

    const int wv   = tid >> 6;          // 0..7
    const int lane = tid & 63;
    const int g    = wv >> 2;           // token group 0,1
    const int s    = wv & 3;            // code slab 0..3
    const int tok  = blockIdx.x * 128 + g * 64 + lane;

    const float* __restrict__ xrow = x + (size_t)tok * DD + (size_t)h * HD;
    const float4* __restrict__ ef4 = (const float4*)e_lds + (size_t)s * 16 * (HD/4);
    const float* __restrict__ cbh  = cbq + h * KK + s * 16;

    float acc[16];
    #pragma unroll
    for (int k = 0; k < 16; ++k) acc[k] = 0.f;

    // numpy-pairwise input_sq: r[d&7] += x[d]^2, d ascending; halves at 128.
    float r0=0.f,r1=0.f,r2=0.f,r3=0.f,r4=0.f,r5=0.f,r6=0.f,r7=0.f;
    float halfA = 0.f;

    float4 n0 = *(const float4*)(xrow + 0);
    float4 n1 = *(const float4*)(xrow + 4);
    float4 n2 = *(const float4*)(xrow + 8);
    float4 n3 = *(const float4*)(xrow + 12);

    for (int c = 0; c < 16; ++c) {       // 16 chunks x 16 dims = 256
        const float4 a0 = n0, a1 = n1, a2 = n2, a3 = n3;
        if (c < 15) {
            const float* p = xrow + (c + 1) * 16;
            n0 = *(const float4*)(p + 0);
            n1 = *(const float4*)(p + 4);
            n2 = *(const float4*)(p + 8);
            n3 = *(const float4*)(p + 12);
        }
        const float xv[16] = { a0.x,a0.y,a0.z,a0.w, a1.x,a1.y,a1.z,a1.w,
                               a2.x,a2.y,a2.z,a2.w, a3.x,a3.y,a3.z,a3.w };
        const int c4 = c * 4;

        // 16 codes in 8 windows of 2; sched_barrier caps in-flight LDS data.
#define KBODY(K) { \
            const float4 e0 = ef4[(K) * (HD/4) + c4 + 0]; \
            const float4 e1 = ef4[(K) * (HD/4) + c4 + 1]; \
            const float4 e2 = ef4[(K) * (HD/4) + c4 + 2]; \
            const float4 e3 = ef4[(K) * (HD/4) + c4 + 3]; \
            float a = acc[K]; \
            a = __builtin_fmaf(e0.x, xv[0],  a); \
            a = __builtin_fmaf(e0.y, xv[1],  a); \
            a = __builtin_fmaf(e0.z, xv[2],  a); \
            a = __builtin_fmaf(e0.w, xv[3],  a); \
            a = __builtin_fmaf(e1.x, xv[4],  a); \
            a = __builtin_fmaf(e1.y, xv[5],  a); \
            a = __builtin_fmaf(e1.z, xv[6],  a); \
            a = __builtin_fmaf(e1.w, xv[7],  a); \
            a = __builtin_fmaf(e2.x, xv[8],  a); \
            a = __builtin_fmaf(e2.y, xv[9],  a); \
            a = __builtin_fmaf(e2.z, xv[10], a); \
            a = __builtin_fmaf(e2.w, xv[11], a); \
            a = __builtin_fmaf(e3.x, xv[12], a); \
            a = __builtin_fmaf(e3.y, xv[13], a); \
            a = __builtin_fmaf(e3.z, xv[14], a); \
            a = __builtin_fmaf(e3.w, xv[15], a); \
            acc[K] = a; }

        KBODY(0)  KBODY(1)  __builtin_amdgcn_sched_barrier(0);
        KBODY(2)  KBODY(3)  __builtin_amdgcn_sched_barrier(0);
        KBODY(4)  KBODY(5)  __builtin_amdgcn_sched_barrier(0);
        KBODY(6)  KBODY(7)  __builtin_amdgcn_sched_barrier(0);
        KBODY(8)  KBODY(9)  __builtin_amdgcn_sched_barrier(0);
        KBODY(10) KBODY(11) __builtin_amdgcn_sched_barrier(0);
        KBODY(12) KBODY(13) __builtin_amdgcn_sched_barrier(0);
        KBODY(14) KBODY(15) __builtin_amdgcn_sched_barrier(0);
#undef KBODY
        {
            #pragma clang fp contract(off)
            r0 = r0 + xv[0]*xv[0];   r1 = r1 + xv[1]*xv[1];
            r2 = r2 + xv[2]*xv[2];   r3 = r3 + xv[3]*xv[3];
            r4 = r4 + xv[4]*xv[4];   r5 = r5 + xv[5]*xv[5];
            r6 = r6 + xv[6]*xv[6];   r7 = r7 + xv[7]*xv[7];
            r0 = r0 + xv[8]*xv[8];   r1 = r1 + xv[9]*xv[9];
            r2 = r2 + xv[10]*xv[10]; r3 = r3 + xv[11]*xv[11];
            r4 = r4 + xv[12]*xv[12]; r5 = r5 + xv[13]*xv[13];
            r6 = r6 + xv[14]*xv[14]; r7 = r7 + xv[15]*xv[15];
        }
        if (c == 7) {   // close first 128-dim block, numpy combine order
            halfA = ((r0 + r1) + (r2 + r3)) + ((r4 + r5) + (r6 + r7));
            r0=r1=r2=r3=r4=r5=r6=r7=0.f;
        }
    }
    const float halfB = ((r0 + r1) + (r2 + r3)) + ((r4 + r5) + (r6 + r7));
    const float isq = halfA + halfB;

    // This wave's 16 codes: dist = (isq + cbq[k]) - 2*dot; strict < argmin.
    float bv = (isq + cbh[0]) - 2.0f * acc[0];
    int   bi = 0;
    #pragma unroll
    for (int k = 1; k < 16; ++k) {
        const float d = (isq + cbh[k]) - 2.0f * acc[k];
        const bool lt = d < bv;
        bv = lt ? d : bv;
        bi = lt ? k : bi;
    }
    vals[wv][lane] = bv;
    idxs[wv][lane] = s * 16 + bi;
    __syncthreads();

    // Per-group combine in slab order (strict < => global first-index).
    if (s == 0) {
        float f  = vals[g * 4 + 0][lane];
        int   fi = idxs[g * 4 + 0][lane];
        #pragma unroll
        for (int w = 1; w < 4; ++w) {
            const float v  = vals[g * 4 + w][lane];
            const int   vi = idxs[g * 4 + w][lane];
            const bool lt = v < f;
            f  = lt ? v  : f;
            fi = lt ? vi : fi;
        }
        out[NDQ + 1 + (size_t)tok * HH + h] = (float)fi;
        fidx[g * 64 + lane] = fi;

        float loss = f;                  // min dist == ||q-x||^2 (~1e-6 rel)
        #pragma unroll
        for (int m = 1; m < 64; m <<= 1) loss += __shfl_xor(loss, m);
        if (lane == 0)
            partial[((size_t)blockIdx.y * gridDim.x + blockIdx.x) * 2 + g] =
                (double)loss;
    }
    __syncthreads();

    // Epilogue: 128 q-rows, 16 per wave, gathered from LDS, coalesced writes.
    for (int t = 0; t < 16; ++t) {
        const int row = wv * 16 + t;
        const int kst = fidx[row];
        const float4 q4 = *(const float4*)(e_lds + (size_t)kst * HD + lane * 4);
        *(float4*)(out + (size_t)(blockIdx.x * 128 + row) * DD
                       + (size_t)h * HD + lane * 4) = q4;
    }
}

__global__ void vq_finalize(const double* __restrict__ partial,
                            float* __restrict__ out)
{
    const int lane = threadIdx.x & 63;
    double s = 0.0;
    for (int i = 0; i < NPART / 64; ++i) s += partial[i * 64 + lane];
    #pragma unroll
    for (int m = 1; m < 64; m <<= 1) s += __shfl_xor(s, m);
    if (lane == 0) {
        const float mv = (float)(s / (double)NDQ);
        out[NDQ] = mv + 0.5f * mv;   // q_latent + 0.5*e_latent (equal values)
    }
}

extern "C" void kernel_launch(void* const* d_in, const int* in_sizes, int n_in,
                              void* d_out, int out_size, void* d_ws, size_t ws_size,
                              hipStream_t stream)
{
    const float* x   = (const float*)d_in[0];
    const float* emb = (const float*)d_in[1];
    float* out = (float*)d_out;
    double* partial = (double*)d_ws;                       // 2048 doubles
    float*  cbq     = (float*)((char*)d_ws + NPART * 8);   // 256 floats

    vq_cbq<<<1, dim3(256), 0, stream>>>(emb, cbq);
    vq_main<<<dim3(NTOK / 128, HH), dim3(512), 0, stream>>>(x, emb, cbq, out, partial);
    vq_finalize<<<1, dim3(64), 0, stream>>>(partial, out);
}

// Round 11
// 209.690 us; speedup vs baseline: 4.9526x; 4.9526x over previous
//
#include <hip/hip_runtime.h>

// Multi-head VQ: inputs (16,2048,1024) f32, embeddings (4,64,256) f32.
// Out flat f32: quantized_st[33554432] | loss[1] | indices[131072 as float].
// R11: codebook lives in REGISTERS (64 VGPR/lane), x streams via LDS.
// Block = 256 thr, 32 tokens, 1 head. lane = (k_local = lane>>2, ds = lane&3);
// wave w owns codes w*16..w*16+16; lane holds e[k][ds*64..+64) (16 float4).
// Token loop: conflict-free broadcast ds_read of x slices + 64 FMA/lane,
// quad shfl-reduce for the dot, butterfly argmin over quads (strict <,
// first-index ties), slab-order cross-wave combine (R6 semantics).
// isq computed in R6's exact numpy-pairwise order by lane=(t,half).
// quantized_st written as q directly (|x+(q-x)-q| ~1e-6 << 1.26 thr);
// loss = min distance (== ||q-x||^2 within ~1e-6 rel).

#define HH   4
#define KK   64
#define HD   256
#define DD   1024
#define NTOK 32768
#define NDQ  33554432ull
#define TPB  32            // tokens per block
#define NBX  (NTOK / TPB)  // 1024 blocks in x
#define NPART (NBX * HH)   // 4096 partials
#define XSTR 68            // padded float stride per (t,ds) 64-dim slice

__global__ void vq_cbq(const float* __restrict__ emb, float* __restrict__ cbq)
{
    const int t = threadIdx.x;               // one per (h,k)
    const float* e = emb + (size_t)t * HD;
    float s = 0.f;
    {
        #pragma clang fp contract(off)
        for (int d = 0; d < HD; ++d) {
            float p = e[d] * e[d];
            s = s + p;
        }
    }
    cbq[t] = s;
}

__global__ __launch_bounds__(256, 2) void vq_main(
    const float* __restrict__ x, const float* __restrict__ emb,
    const float* __restrict__ cbq, float* __restrict__ out,
    double* __restrict__ partial)
{
    __shared__ __align__(16) float x_lds[TPB * 4 * XSTR];  // 34816 B
    __shared__ float isq_lds[TPB];
    __shared__ float vals[4][TPB];
    __shared__ int   idxs[4][TPB];
    __shared__ int   bi_lds[TPB];

    const int h    = blockIdx.y;
    const int wv   = threadIdx.x >> 6;
    const int lane = threadIdx.x & 63;
    const int tok0 = blockIdx.x * TPB;

    const float* __restrict__ eh = emb + (size_t)h * (KK * HD);

    // ---- Phase A: this wave's 16-code e-slab into registers (one-time) ----
    const int kl = lane >> 2;          // 0..15 code within slab
    const int ds = lane & 3;           // 0..3 dim slice (64 dims each)
    const int k  = wv * 16 + kl;       // global code id
    float4 ev[16];
    {
        const float4* __restrict__ ep =
            (const float4*)(eh + (size_t)k * HD + ds * 64);
        #pragma unroll
        for (int j = 0; j < 16; ++j) ev[j] = ep[j];
    }
    const float cbk = cbq[h * KK + k];

    // ---- Phase B: stage x-tile to LDS + isq (R6's exact pairwise order).
    // lane = (token tl = lane>>1, half hf = lane&1); redundant across waves
    // (benign same-value LDS races; HBM reads once, rest L2).
    {
        const int tl = lane >> 1;
        const int hf = lane & 1;
        const float* __restrict__ xr =
            x + (size_t)(tok0 + tl) * DD + h * HD + hf * 128;
        float r0=0.f,r1=0.f,r2=0.f,r3=0.f,r4=0.f,r5=0.f,r6=0.f,r7=0.f;
        #pragma unroll
        for (int cc = 0; cc < 8; ++cc) {
            const float4 v0 = ((const float4*)xr)[cc * 4 + 0];
            const float4 v1 = ((const float4*)xr)[cc * 4 + 1];
            const float4 v2 = ((const float4*)xr)[cc * 4 + 2];
            const float4 v3 = ((const float4*)xr)[cc * 4 + 3];
            float* dst = x_lds + ((tl * 4) + (hf * 2 + (cc >> 2))) * XSTR
                               + (cc & 3) * 16;
            ((float4*)dst)[0] = v0; ((float4*)dst)[1] = v1;
            ((float4*)dst)[2] = v2; ((float4*)dst)[3] = v3;
            {
                #pragma clang fp contract(off)
                r0 = r0 + v0.x*v0.x;  r1 = r1 + v0.y*v0.y;
                r2 = r2 + v0.z*v0.z;  r3 = r3 + v0.w*v0.w;
                r4 = r4 + v1.x*v1.x;  r5 = r5 + v1.y*v1.y;
                r6 = r6 + v1.z*v1.z;  r7 = r7 + v1.w*v1.w;
                r0 = r0 + v2.x*v2.x;  r1 = r1 + v2.y*v2.y;
                r2 = r2 + v2.z*v2.z;  r3 = r3 + v2.w*v2.w;
                r4 = r4 + v3.x*v3.x;  r5 = r5 + v3.y*v3.y;
                r6 = r6 + v3.z*v3.z;  r7 = r7 + v3.w*v3.w;
            }
        }
        const float hs = ((r0 + r1) + (r2 + r3)) + ((r4 + r5) + (r6 + r7));
        const float ho = __shfl_xor(hs, 1);
        if (hf == 0) isq_lds[tl] = hs + ho;   // halfA + halfB, numpy order
    }
    __syncthreads();

    // ---- Phase C: token loop — zero global/scalar loads on hot path ----
    #pragma unroll 1
    for (int t = 0; t < TPB; ++t) {
        const float* __restrict__ xb = x_lds + (t * 4 + ds) * XSTR;
        float p = 0.f;
        #pragma unroll
        for (int j = 0; j < 16; ++j) {
            const float4 xv = ((const float4*)xb)[j];
            p = __builtin_fmaf(ev[j].x, xv.x, p);
            p = __builtin_fmaf(ev[j].y, xv.y, p);
            p = __builtin_fmaf(ev[j].z, xv.z, p);
            p = __builtin_fmaf(ev[j].w, xv.w, p);
        }
        // quad reduce: all 4 ds-lanes end with identical dot (same tree)
        p += __shfl_xor(p, 1);
        p += __shfl_xor(p, 2);
        float bv = (isq_lds[t] + cbk) - 2.0f * p;
        int   bi = k;
        // argmin over the wave's 16 codes (quads); strict <, first-index
        #pragma unroll
        for (int m = 4; m < 64; m <<= 1) {
            const float ov = __shfl_xor(bv, m);
            const int   oi = __shfl_xor(bi, m);
            if (ov < bv || (ov == bv && oi < bi)) { bv = ov; bi = oi; }
        }
        if (lane == 0) { vals[wv][t] = bv; idxs[wv][t] = bi; }
    }
    __syncthreads();

    // ---- Phase D: cross-wave combine in slab order (first-index ties) ----
    if (wv == 0 && lane < TPB) {
        const int t = lane;
        float f  = vals[0][t];
        int   fi = idxs[0][t];
        #pragma unroll
        for (int w = 1; w < 4; ++w) {
            const float v  = vals[w][t];
            const int   vi = idxs[w][t];
            const bool lt = v < f;
            f  = lt ? v  : f;
            fi = lt ? vi : fi;
        }
        out[NDQ + 1 + (size_t)(tok0 + t) * HH + h] = (float)fi;
        bi_lds[t] = fi;
        float ls = f;                    // min dist == ||q-x||^2 (~1e-6 rel)
        #pragma unroll
        for (int m = 1; m < TPB; m <<= 1) ls += __shfl_xor(ls, m);
        if (t == 0)
            partial[(size_t)h * NBX + blockIdx.x] = (double)ls;
    }
    __syncthreads();

    // ---- Phase E: q-row writes (8 rows/wave), gather from L2 codebook ----
    #pragma unroll
    for (int i = 0; i < TPB / 4; ++i) {
        const int row = wv * (TPB / 4) + i;
        const int kst = bi_lds[row];
        const float4 q4 = *(const float4*)(eh + (size_t)kst * HD + lane * 4);
        *(float4*)(out + (size_t)(tok0 + row) * DD + h * HD + lane * 4) = q4;
    }
}

__global__ void vq_finalize(const double* __restrict__ partial,
                            float* __restrict__ out)
{
    const int lane = threadIdx.x & 63;
    double s = 0.0;
    for (int i = 0; i < NPART / 64; ++i) s += partial[i * 64 + lane];
    #pragma unroll
    for (int m = 1; m < 64; m <<= 1) s += __shfl_xor(s, m);
    if (lane == 0) {
        const float mv = (float)(s / (double)NDQ);
        out[NDQ] = mv + 0.5f * mv;   // q_latent + 0.5*e_latent (equal values)
    }
}

extern "C" void kernel_launch(void* const* d_in, const int* in_sizes, int n_in,
                              void* d_out, int out_size, void* d_ws, size_t ws_size,
                              hipStream_t stream)
{
    const float* x   = (const float*)d_in[0];
    const float* emb = (const float*)d_in[1];
    float* out = (float*)d_out;
    double* partial = (double*)d_ws;                       // 4096 doubles
    float*  cbq     = (float*)((char*)d_ws + NPART * 8);   // 256 floats

    vq_cbq<<<1, dim3(256), 0, stream>>>(emb, cbq);
    vq_main<<<dim3(NBX, HH), dim3(256), 0, stream>>>(x, emb, cbq, out, partial);
    vq_finalize<<<1, dim3(64), 0, stream>>>(partial, out);
}

// Round 12
// 172.566 us; speedup vs baseline: 6.0180x; 1.2151x over previous
//
#include <hip/hip_runtime.h>

// Multi-head VQ: inputs (16,2048,1024) f32, embeddings (4,64,256) f32.
// Out flat f32: quantized_st[33554432] | loss[1] | indices[131072 as float].
// R12: R11 skeleton (e in VGPRs: lane=(kl=lane>>2, ds=lane&3) holds 16
// float4 of e[wv*16+kl][ds*64..+64)); x streamed through LDS. Changes:
//  - 4 dot accumulators (chain depth 64->16)
//  - argmin via dist_lds matrix + in-lane ascending-k scan (exact numpy
//    first-index ties), replacing 4-level butterflies
//  - Phase B exec-masked to 8 tokens/wave (dedup: 4x fewer conflicts/loads)
// quantized_st written as q directly (|x+(q-x)-q| ~1e-6 << 1.26 thr);
// loss = min distance (== ||q-x||^2 within ~1e-6 rel).

#define HH   4
#define KK   64
#define HD   256
#define DD   1024
#define NTOK 32768
#define NDQ  33554432ull
#define TPB  32            // tokens per block
#define NBX  (NTOK / TPB)  // 1024 blocks in x
#define NPART (NBX * HH)   // 4096 partials
#define XSTR 68            // padded float stride per (t,ds) 64-dim slice
#define DSTR 68            // padded float stride per-token dist row

__global__ void vq_cbq(const float* __restrict__ emb, float* __restrict__ cbq)
{
    const int t = threadIdx.x;               // one per (h,k)
    const float* e = emb + (size_t)t * HD;
    float s = 0.f;
    {
        #pragma clang fp contract(off)
        for (int d = 0; d < HD; ++d) {
            float p = e[d] * e[d];
            s = s + p;
        }
    }
    cbq[t] = s;
}

__global__ __launch_bounds__(256, 2) void vq_main(
    const float* __restrict__ x, const float* __restrict__ emb,
    const float* __restrict__ cbq, float* __restrict__ out,
    double* __restrict__ partial)
{
    __shared__ __align__(16) float x_lds[TPB * 4 * XSTR];  // 34816 B
    __shared__ float dist_lds[TPB * DSTR];                 //  8704 B
    __shared__ float isq_lds[TPB];
    __shared__ int   bi_lds[TPB];

    const int h    = blockIdx.y;
    const int wv   = threadIdx.x >> 6;
    const int lane = threadIdx.x & 63;
    const int tok0 = blockIdx.x * TPB;

    const float* __restrict__ eh = emb + (size_t)h * (KK * HD);

    // ---- Phase A: wave's 16-code e-slab into registers (one-time) ----
    const int kl = lane >> 2;          // 0..15 code within slab
    const int ds = lane & 3;           // 0..3 dim slice (64 dims each)
    const int k  = wv * 16 + kl;       // global code id
    float4 ev[16];
    {
        const float4* __restrict__ ep =
            (const float4*)(eh + (size_t)k * HD + ds * 64);
        #pragma unroll
        for (int j = 0; j < 16; ++j) ev[j] = ep[j];
    }
    const float cbk = cbq[h * KK + k];

    // ---- Phase B: stage x-tile + isq (R6's exact pairwise order).
    // Wave wv handles tokens [wv*8, wv*8+8) only (exec-masked dedup).
    {
        const int tl = lane >> 1;
        const int hf = lane & 1;
        if ((tl >> 3) == wv) {
            const float* __restrict__ xr =
                x + (size_t)(tok0 + tl) * DD + h * HD + hf * 128;
            float r0=0.f,r1=0.f,r2=0.f,r3=0.f,r4=0.f,r5=0.f,r6=0.f,r7=0.f;
            #pragma unroll
            for (int cc = 0; cc < 8; ++cc) {
                const float4 v0 = ((const float4*)xr)[cc * 4 + 0];
                const float4 v1 = ((const float4*)xr)[cc * 4 + 1];
                const float4 v2 = ((const float4*)xr)[cc * 4 + 2];
                const float4 v3 = ((const float4*)xr)[cc * 4 + 3];
                float* dst = x_lds + ((tl * 4) + (hf * 2 + (cc >> 2))) * XSTR
                                   + (cc & 3) * 16;
                ((float4*)dst)[0] = v0; ((float4*)dst)[1] = v1;
                ((float4*)dst)[2] = v2; ((float4*)dst)[3] = v3;
                {
                    #pragma clang fp contract(off)
                    r0 = r0 + v0.x*v0.x;  r1 = r1 + v0.y*v0.y;
                    r2 = r2 + v0.z*v0.z;  r3 = r3 + v0.w*v0.w;
                    r4 = r4 + v1.x*v1.x;  r5 = r5 + v1.y*v1.y;
                    r6 = r6 + v1.z*v1.z;  r7 = r7 + v1.w*v1.w;
                    r0 = r0 + v2.x*v2.x;  r1 = r1 + v2.y*v2.y;
                    r2 = r2 + v2.z*v2.z;  r3 = r3 + v2.w*v2.w;
                    r4 = r4 + v3.x*v3.x;  r5 = r5 + v3.y*v3.y;
                    r6 = r6 + v3.z*v3.z;  r7 = r7 + v3.w*v3.w;
                }
            }
            const float hs = ((r0 + r1) + (r2 + r3)) + ((r4 + r5) + (r6 + r7));
            const float ho = __shfl_xor(hs, 1);
            if (hf == 0) isq_lds[tl] = hs + ho;  // halfA + halfB, numpy order
        }
    }
    __syncthreads();

    // ---- Phase C: dot loop. Broadcast ds_reads, 4 acc chains, quad
    // reduce, leader writes dist row (16 consecutive banks, no conflict).
    #pragma unroll 1
    for (int t = 0; t < TPB; ++t) {
        const float4* __restrict__ xb =
            (const float4*)(x_lds + (t * 4 + ds) * XSTR);
        float p0 = 0.f, p1 = 0.f, p2 = 0.f, p3 = 0.f;
        #pragma unroll
        for (int j = 0; j < 16; j += 4) {
            const float4 xa = xb[j + 0];
            const float4 xbv = xb[j + 1];
            const float4 xc = xb[j + 2];
            const float4 xd = xb[j + 3];
            p0 = __builtin_fmaf(ev[j+0].x, xa.x, p0);
            p0 = __builtin_fmaf(ev[j+0].y, xa.y, p0);
            p0 = __builtin_fmaf(ev[j+0].z, xa.z, p0);
            p0 = __builtin_fmaf(ev[j+0].w, xa.w, p0);
            p1 = __builtin_fmaf(ev[j+1].x, xbv.x, p1);
            p1 = __builtin_fmaf(ev[j+1].y, xbv.y, p1);
            p1 = __builtin_fmaf(ev[j+1].z, xbv.z, p1);
            p1 = __builtin_fmaf(ev[j+1].w, xbv.w, p1);
            p2 = __builtin_fmaf(ev[j+2].x, xc.x, p2);
            p2 = __builtin_fmaf(ev[j+2].y, xc.y, p2);
            p2 = __builtin_fmaf(ev[j+2].z, xc.z, p2);
            p2 = __builtin_fmaf(ev[j+2].w, xc.w, p2);
            p3 = __builtin_fmaf(ev[j+3].x, xd.x, p3);
            p3 = __builtin_fmaf(ev[j+3].y, xd.y, p3);
            p3 = __builtin_fmaf(ev[j+3].z, xd.z, p3);
            p3 = __builtin_fmaf(ev[j+3].w, xd.w, p3);
        }
        float p = (p0 + p1) + (p2 + p3);
        p += __shfl_xor(p, 1);
        p += __shfl_xor(p, 2);
        if (ds == 0)
            dist_lds[t * DSTR + k] = (isq_lds[t] + cbk) - 2.0f * p;
    }
    __syncthreads();

    // ---- Phase D: per-token in-lane argmin (ascending k, strict < =>
    // exact numpy first-index). Lane t of wave 0 owns token t.
    if (wv == 0 && lane < TPB) {
        const int t = lane;
        const float* __restrict__ dr = dist_lds + t * DSTR;
        float f  = dr[0];
        int   fi = 0;
        #pragma unroll 8
        for (int kk = 1; kk < KK; ++kk) {
            const float v = dr[kk];
            const bool lt = v < f;
            f  = lt ? v  : f;
            fi = lt ? kk : fi;
        }
        out[NDQ + 1 + (size_t)(tok0 + t) * HH + h] = (float)fi;
        bi_lds[t] = fi;
        float ls = f;                    // min dist == ||q-x||^2 (~1e-6 rel)
        #pragma unroll
        for (int m = 1; m < TPB; m <<= 1) ls += __shfl_xor(ls, m);
        if (t == 0)
            partial[(size_t)h * NBX + blockIdx.x] = (double)ls;
    }
    __syncthreads();

    // ---- Phase E: q-row writes (8 rows/wave), gather from L2 codebook ----
    #pragma unroll
    for (int i = 0; i < TPB / 4; ++i) {
        const int row = wv * (TPB / 4) + i;
        const int kst = bi_lds[row];
        const float4 q4 = *(const float4*)(eh + (size_t)kst * HD + lane * 4);
        *(float4*)(out + (size_t)(tok0 + row) * DD + h * HD + lane * 4) = q4;
    }
}

__global__ void vq_finalize(const double* __restrict__ partial,
                            float* __restrict__ out)
{
    const int lane = threadIdx.x & 63;
    double s = 0.0;
    for (int i = 0; i < NPART / 64; ++i) s += partial[i * 64 + lane];
    #pragma unroll
    for (int m = 1; m < 64; m <<= 1) s += __shfl_xor(s, m);
    if (lane == 0) {
        const float mv = (float)(s / (double)NDQ);
        out[NDQ] = mv + 0.5f * mv;   // q_latent + 0.5*e_latent (equal values)
    }
}

extern "C" void kernel_launch(void* const* d_in, const int* in_sizes, int n_in,
                              void* d_out, int out_size, void* d_ws, size_t ws_size,
                              hipStream_t stream)
{
    const float* x   = (const float*)d_in[0];
    const float* emb = (const float*)d_in[1];
    float* out = (float*)d_out;
    double* partial = (double*)d_ws;                       // 4096 doubles
    float*  cbq     = (float*)((char*)d_ws + NPART * 8);   // 256 floats

    vq_cbq<<<1, dim3(256), 0, stream>>>(emb, cbq);
    vq_main<<<dim3(NBX, HH), dim3(256), 0, stream>>>(x, emb, cbq, out, partial);
    vq_finalize<<<1, dim3(64), 0, stream>>>(partial, out);
}

// Round 13
// 166.769 us; speedup vs baseline: 6.2272x; 1.0348x over previous
//
#include <hip/hip_runtime.h>

// Multi-head VQ: inputs (16,2048,1024) f32, embeddings (4,64,256) f32.
// Out flat f32: quantized_st[33554432] | loss[1] | indices[131072 as float].
// R13: like R12 (e in VGPRs, x via LDS) but lane = (kq=lane>>4, ds=lane&15)
// holds 4 codes x 16 dims -> each x-float loaded from LDS feeds 4 FMAs
// (was 1). LDS read traffic drops 4x; dot reduced over 16 ds-lanes via
// DPP shfl_xor (VALU pipe). x slices skew-20 floats (2-way worst = free).
// dist_lds matrix + in-lane ascending-k scan keeps exact numpy first-index
// ties. isq byte-identical to R6. quantized_st written as q directly
// (|x+(q-x)-q| ~1e-6 << 1.26 thr); loss = min distance.

#define HH   4
#define KK   64
#define HD   256
#define DD   1024
#define NTOK 32768
#define NDQ  33554432ull
#define TPB  32            // tokens per block
#define NBX  (NTOK / TPB)  // 1024 blocks in x
#define NPART (NBX * HH)   // 4096 partials
#define XSTR 320           // floats per token row (16 slices * skew 20)
#define DSTR 68            // padded float stride per-token dist row

__global__ void vq_cbq(const float* __restrict__ emb, float* __restrict__ cbq)
{
    const int t = threadIdx.x;               // one per (h,k)
    const float* e = emb + (size_t)t * HD;
    float s = 0.f;
    {
        #pragma clang fp contract(off)
        for (int d = 0; d < HD; ++d) {
            float p = e[d] * e[d];
            s = s + p;
        }
    }
    cbq[t] = s;
}

__global__ __launch_bounds__(256, 2) void vq_main(
    const float* __restrict__ x, const float* __restrict__ emb,
    const float* __restrict__ cbq, float* __restrict__ out,
    double* __restrict__ partial)
{
    __shared__ __align__(16) float x_lds[TPB * XSTR];      // 40960 B
    __shared__ __align__(16) float dist_lds[TPB * DSTR];   //  8704 B
    __shared__ float isq_lds[TPB];
    __shared__ int   bi_lds[TPB];

    const int h    = blockIdx.y;
    const int wv   = threadIdx.x >> 6;
    const int lane = threadIdx.x & 63;
    const int tok0 = blockIdx.x * TPB;

    const float* __restrict__ eh = emb + (size_t)h * (KK * HD);

    // ---- Phase A: lane holds 4 codes x 16 dims of e (16 float4) ----
    const int kq = lane >> 4;          // 0..3 code quad within wave slab
    const int ds = lane & 15;          // 0..15 dim slice (16 dims each)
    const int kbase = wv * 16 + kq * 4;
    float4 ev[4][4];
    #pragma unroll
    for (int m = 0; m < 4; ++m) {
        const float4* __restrict__ ep =
            (const float4*)(eh + (size_t)(kbase + m) * HD + ds * 16);
        #pragma unroll
        for (int j = 0; j < 4; ++j) ev[m][j] = ep[j];
    }
    const float cb0 = cbq[h * KK + kbase + 0];
    const float cb1 = cbq[h * KK + kbase + 1];
    const float cb2 = cbq[h * KK + kbase + 2];
    const float cb3 = cbq[h * KK + kbase + 3];

    // ---- Phase B: stage x-tile + isq (R6's exact pairwise order).
    // Wave wv handles tokens [wv*8, wv*8+8) only (exec-masked dedup).
    {
        const int tl = lane >> 1;
        const int hf = lane & 1;
        if ((tl >> 3) == wv) {
            const float* __restrict__ xr =
                x + (size_t)(tok0 + tl) * DD + h * HD + hf * 128;
            float r0=0.f,r1=0.f,r2=0.f,r3=0.f,r4=0.f,r5=0.f,r6=0.f,r7=0.f;
            #pragma unroll
            for (int cc = 0; cc < 8; ++cc) {
                const float4 v0 = ((const float4*)xr)[cc * 4 + 0];
                const float4 v1 = ((const float4*)xr)[cc * 4 + 1];
                const float4 v2 = ((const float4*)xr)[cc * 4 + 2];
                const float4 v3 = ((const float4*)xr)[cc * 4 + 3];
                float* dst = x_lds + tl * XSTR + (hf * 8 + cc) * 20;
                ((float4*)dst)[0] = v0; ((float4*)dst)[1] = v1;
                ((float4*)dst)[2] = v2; ((float4*)dst)[3] = v3;
                {
                    #pragma clang fp contract(off)
                    r0 = r0 + v0.x*v0.x;  r1 = r1 + v0.y*v0.y;
                    r2 = r2 + v0.z*v0.z;  r3 = r3 + v0.w*v0.w;
                    r4 = r4 + v1.x*v1.x;  r5 = r5 + v1.y*v1.y;
                    r6 = r6 + v1.z*v1.z;  r7 = r7 + v1.w*v1.w;
                    r0 = r0 + v2.x*v2.x;  r1 = r1 + v2.y*v2.y;
                    r2 = r2 + v2.z*v2.z;  r3 = r3 + v2.w*v2.w;
                    r4 = r4 + v3.x*v3.x;  r5 = r5 + v3.y*v3.y;
                    r6 = r6 + v3.z*v3.z;  r7 = r7 + v3.w*v3.w;
                }
            }
            const float hs = ((r0 + r1) + (r2 + r3)) + ((r4 + r5) + (r6 + r7));
            const float ho = __shfl_xor(hs, 1);
            if (hf == 0) isq_lds[tl] = hs + ho;  // halfA + halfB, numpy order
        }
    }
    __syncthreads();

    // ---- Phase C: dot loop. 4 float4 LDS reads feed 64 FMAs (4 codes),
    // DPP shfl_xor tree over 16 ds-lanes, ds==0 writes a float4 of dists.
    #pragma unroll 1
    for (int t = 0; t < TPB; ++t) {
        const float4* __restrict__ xb =
            (const float4*)(x_lds + t * XSTR + ds * 20);
        float p0 = 0.f, p1 = 0.f, p2 = 0.f, p3 = 0.f;
        #pragma unroll
        for (int j = 0; j < 4; ++j) {
            const float4 xv = xb[j];
            p0 = __builtin_fmaf(ev[0][j].x, xv.x, p0);
            p0 = __builtin_fmaf(ev[0][j].y, xv.y, p0);
            p0 = __builtin_fmaf(ev[0][j].z, xv.z, p0);
            p0 = __builtin_fmaf(ev[0][j].w, xv.w, p0);
            p1 = __builtin_fmaf(ev[1][j].x, xv.x, p1);
            p1 = __builtin_fmaf(ev[1][j].y, xv.y, p1);
            p1 = __builtin_fmaf(ev[1][j].z, xv.z, p1);
            p1 = __builtin_fmaf(ev[1][j].w, xv.w, p1);
            p2 = __builtin_fmaf(ev[2][j].x, xv.x, p2);
            p2 = __builtin_fmaf(ev[2][j].y, xv.y, p2);
            p2 = __builtin_fmaf(ev[2][j].z, xv.z, p2);
            p2 = __builtin_fmaf(ev[2][j].w, xv.w, p2);
            p3 = __builtin_fmaf(ev[3][j].x, xv.x, p3);
            p3 = __builtin_fmaf(ev[3][j].y, xv.y, p3);
            p3 = __builtin_fmaf(ev[3][j].z, xv.z, p3);
            p3 = __builtin_fmaf(ev[3][j].w, xv.w, p3);
        }
        // reduce over the 16 ds-lanes (DPP, VALU pipe)
        #pragma unroll
        for (int m = 1; m < 16; m <<= 1) {
            p0 += __shfl_xor(p0, m);
            p1 += __shfl_xor(p1, m);
            p2 += __shfl_xor(p2, m);
            p3 += __shfl_xor(p3, m);
        }
        if (ds == 0) {
            const float iq = isq_lds[t];
            float4 dv;
            dv.x = (iq + cb0) - 2.0f * p0;
            dv.y = (iq + cb1) - 2.0f * p1;
            dv.z = (iq + cb2) - 2.0f * p2;
            dv.w = (iq + cb3) - 2.0f * p3;
            *(float4*)(dist_lds + t * DSTR + kbase) = dv;
        }
    }
    __syncthreads();

    // ---- Phase D: per-token in-lane argmin (ascending k, strict < =>
    // exact numpy first-index). Lane t of wave 0 owns token t.
    if (wv == 0 && lane < TPB) {
        const int t = lane;
        const float* __restrict__ dr = dist_lds + t * DSTR;
        float f  = dr[0];
        int   fi = 0;
        #pragma unroll 8
        for (int kk = 1; kk < KK; ++kk) {
            const float v = dr[kk];
            const bool lt = v < f;
            f  = lt ? v  : f;
            fi = lt ? kk : fi;
        }
        out[NDQ + 1 + (size_t)(tok0 + t) * HH + h] = (float)fi;
        bi_lds[t] = fi;
        float ls = f;                    // min dist == ||q-x||^2 (~1e-6 rel)
        #pragma unroll
        for (int m = 1; m < TPB; m <<= 1) ls += __shfl_xor(ls, m);
        if (t == 0)
            partial[(size_t)h * NBX + blockIdx.x] = (double)ls;
    }
    __syncthreads();

    // ---- Phase E: q-row writes (8 rows/wave), gather from L2 codebook ----
    #pragma unroll
    for (int i = 0; i < TPB / 4; ++i) {
        const int row = wv * (TPB / 4) + i;
        const int kst = bi_lds[row];
        const float4 q4 = *(const float4*)(eh + (size_t)kst * HD + lane * 4);
        *(float4*)(out + (size_t)(tok0 + row) * DD + h * HD + lane * 4) = q4;
    }
}

__global__ void vq_finalize(const double* __restrict__ partial,
                            float* __restrict__ out)
{
    const int lane = threadIdx.x & 63;
    double s = 0.0;
    for (int i = 0; i < NPART / 64; ++i) s += partial[i * 64 + lane];
    #pragma unroll
    for (int m = 1; m < 64; m <<= 1) s += __shfl_xor(s, m);
    if (lane == 0) {
        const float mv = (float)(s / (double)NDQ);
        out[NDQ] = mv + 0.5f * mv;   // q_latent + 0.5*e_latent (equal values)
    }
}

extern "C" void kernel_launch(void* const* d_in, const int* in_sizes, int n_in,
                              void* d_out, int out_size, void* d_ws, size_t ws_size,
                              hipStream_t stream)
{
    const float* x   = (const float*)d_in[0];
    const float* emb = (const float*)d_in[1];
    float* out = (float*)d_out;
    double* partial = (double*)d_ws;                       // 4096 doubles
    float*  cbq     = (float*)((char*)d_ws + NPART * 8);   // 256 floats

    vq_cbq<<<1, dim3(256), 0, stream>>>(emb, cbq);
    vq_main<<<dim3(NBX, HH), dim3(256), 0, stream>>>(x, emb, cbq, out, partial);
    vq_finalize<<<1, dim3(64), 0, stream>>>(partial, out);
}

// Round 14
// 155.458 us; speedup vs baseline: 6.6803x; 1.0728x over previous
//
#include <hip/hip_runtime.h>

// Multi-head VQ: inputs (16,2048,1024) f32, embeddings (4,64,256) f32.
// Out flat f32: quantized_st[33554432] | loss[1] | indices[131072 as float].
// R14 = R13 with two fixes:
//  - XSTR 320->324: Phase B write bank-quad now (tl*4 + cc*20) mod 32,
//    spreading 8 active tl over 8 quads (was: all lanes same quad = 16-way).
//  - Phase C token loop unrolled x2 (independent A/B chains) so FMA-chain
//    and shuffle-tree latency overlap across tokens.
// lane=(kq=lane>>4, ds=lane&15) holds 4 codes x 16 dims of e in VGPRs.
// dist_lds + in-lane ascending-k scan keeps exact numpy first-index ties.
// isq byte-identical to R6. quantized_st written as q directly
// (|x+(q-x)-q| ~1e-6 << 1.26 thr); loss = min distance.

#define HH   4
#define KK   64
#define HD   256
#define DD   1024
#define NTOK 32768
#define NDQ  33554432ull
#define TPB  32            // tokens per block
#define NBX  (NTOK / TPB)  // 1024 blocks in x
#define NPART (NBX * HH)   // 4096 partials
#define XSTR 324           // floats per token row (16 slices * 20 + 4 skew)
#define DSTR 68            // padded float stride per-token dist row

__global__ void vq_cbq(const float* __restrict__ emb, float* __restrict__ cbq)
{
    const int t = threadIdx.x;               // one per (h,k)
    const float* e = emb + (size_t)t * HD;
    float s = 0.f;
    {
        #pragma clang fp contract(off)
        for (int d = 0; d < HD; ++d) {
            float p = e[d] * e[d];
            s = s + p;
        }
    }
    cbq[t] = s;
}

__global__ __launch_bounds__(256, 2) void vq_main(
    const float* __restrict__ x, const float* __restrict__ emb,
    const float* __restrict__ cbq, float* __restrict__ out,
    double* __restrict__ partial)
{
    __shared__ __align__(16) float x_lds[TPB * XSTR];      // 41472 B
    __shared__ __align__(16) float dist_lds[TPB * DSTR];   //  8704 B
    __shared__ float isq_lds[TPB];
    __shared__ int   bi_lds[TPB];

    const int h    = blockIdx.y;
    const int wv   = threadIdx.x >> 6;
    const int lane = threadIdx.x & 63;
    const int tok0 = blockIdx.x * TPB;

    const float* __restrict__ eh = emb + (size_t)h * (KK * HD);

    // ---- Phase A: lane holds 4 codes x 16 dims of e (16 float4) ----
    const int kq = lane >> 4;          // 0..3 code quad within wave slab
    const int ds = lane & 15;          // 0..15 dim slice (16 dims each)
    const int kbase = wv * 16 + kq * 4;
    float4 ev[4][4];
    #pragma unroll
    for (int m = 0; m < 4; ++m) {
        const float4* __restrict__ ep =
            (const float4*)(eh + (size_t)(kbase + m) * HD + ds * 16);
        #pragma unroll
        for (int j = 0; j < 4; ++j) ev[m][j] = ep[j];
    }
    const float cb0 = cbq[h * KK + kbase + 0];
    const float cb1 = cbq[h * KK + kbase + 1];
    const float cb2 = cbq[h * KK + kbase + 2];
    const float cb3 = cbq[h * KK + kbase + 3];

    // ---- Phase B: stage x-tile + isq (R6's exact pairwise order).
    // Wave wv handles tokens [wv*8, wv*8+8) only (exec-masked dedup).
    {
        const int tl = lane >> 1;
        const int hf = lane & 1;
        if ((tl >> 3) == wv) {
            const float* __restrict__ xr =
                x + (size_t)(tok0 + tl) * DD + h * HD + hf * 128;
            float r0=0.f,r1=0.f,r2=0.f,r3=0.f,r4=0.f,r5=0.f,r6=0.f,r7=0.f;
            #pragma unroll
            for (int cc = 0; cc < 8; ++cc) {
                const float4 v0 = ((const float4*)xr)[cc * 4 + 0];
                const float4 v1 = ((const float4*)xr)[cc * 4 + 1];
                const float4 v2 = ((const float4*)xr)[cc * 4 + 2];
                const float4 v3 = ((const float4*)xr)[cc * 4 + 3];
                float* dst = x_lds + tl * XSTR + (hf * 8 + cc) * 20;
                ((float4*)dst)[0] = v0; ((float4*)dst)[1] = v1;
                ((float4*)dst)[2] = v2; ((float4*)dst)[3] = v3;
                {
                    #pragma clang fp contract(off)
                    r0 = r0 + v0.x*v0.x;  r1 = r1 + v0.y*v0.y;
                    r2 = r2 + v0.z*v0.z;  r3 = r3 + v0.w*v0.w;
                    r4 = r4 + v1.x*v1.x;  r5 = r5 + v1.y*v1.y;
                    r6 = r6 + v1.z*v1.z;  r7 = r7 + v1.w*v1.w;
                    r0 = r0 + v2.x*v2.x;  r1 = r1 + v2.y*v2.y;
                    r2 = r2 + v2.z*v2.z;  r3 = r3 + v2.w*v2.w;
                    r4 = r4 + v3.x*v3.x;  r5 = r5 + v3.y*v3.y;
                    r6 = r6 + v3.z*v3.z;  r7 = r7 + v3.w*v3.w;
                }
            }
            const float hs = ((r0 + r1) + (r2 + r3)) + ((r4 + r5) + (r6 + r7));
            const float ho = __shfl_xor(hs, 1);
            if (hf == 0) isq_lds[tl] = hs + ho;  // halfA + halfB, numpy order
        }
    }
    __syncthreads();

    // ---- Phase C: dot loop, 2 tokens per iteration (independent chains).
    #pragma unroll 1
    for (int t = 0; t < TPB; t += 2) {
        const float4* __restrict__ xbA =
            (const float4*)(x_lds + t * XSTR + ds * 20);
        const float4* __restrict__ xbB =
            (const float4*)(x_lds + (t + 1) * XSTR + ds * 20);
        float pA0=0.f, pA1=0.f, pA2=0.f, pA3=0.f;
        float pB0=0.f, pB1=0.f, pB2=0.f, pB3=0.f;
        #pragma unroll
        for (int j = 0; j < 4; ++j) {
            const float4 xA = xbA[j];
            const float4 xB = xbB[j];
            pA0 = __builtin_fmaf(ev[0][j].x, xA.x, pA0);
            pA0 = __builtin_fmaf(ev[0][j].y, xA.y, pA0);
            pA0 = __builtin_fmaf(ev[0][j].z, xA.z, pA0);
            pA0 = __builtin_fmaf(ev[0][j].w, xA.w, pA0);
            pA1 = __builtin_fmaf(ev[1][j].x, xA.x, pA1);
            pA1 = __builtin_fmaf(ev[1][j].y, xA.y, pA1);
            pA1 = __builtin_fmaf(ev[1][j].z, xA.z, pA1);
            pA1 = __builtin_fmaf(ev[1][j].w, xA.w, pA1);
            pA2 = __builtin_fmaf(ev[2][j].x, xA.x, pA2);
            pA2 = __builtin_fmaf(ev[2][j].y, xA.y, pA2);
            pA2 = __builtin_fmaf(ev[2][j].z, xA.z, pA2);
            pA2 = __builtin_fmaf(ev[2][j].w, xA.w, pA2);
            pA3 = __builtin_fmaf(ev[3][j].x, xA.x, pA3);
            pA3 = __builtin_fmaf(ev[3][j].y, xA.y, pA3);
            pA3 = __builtin_fmaf(ev[3][j].z, xA.z, pA3);
            pA3 = __builtin_fmaf(ev[3][j].w, xA.w, pA3);
            pB0 = __builtin_fmaf(ev[0][j].x, xB.x, pB0);
            pB0 = __builtin_fmaf(ev[0][j].y, xB.y, pB0);
            pB0 = __builtin_fmaf(ev[0][j].z, xB.z, pB0);
            pB0 = __builtin_fmaf(ev[0][j].w, xB.w, pB0);
            pB1 = __builtin_fmaf(ev[1][j].x, xB.x, pB1);
            pB1 = __builtin_fmaf(ev[1][j].y, xB.y, pB1);
            pB1 = __builtin_fmaf(ev[1][j].z, xB.z, pB1);
            pB1 = __builtin_fmaf(ev[1][j].w, xB.w, pB1);
            pB2 = __builtin_fmaf(ev[2][j].x, xB.x, pB2);
            pB2 = __builtin_fmaf(ev[2][j].y, xB.y, pB2);
            pB2 = __builtin_fmaf(ev[2][j].z, xB.z, pB2);
            pB2 = __builtin_fmaf(ev[2][j].w, xB.w, pB2);
            pB3 = __builtin_fmaf(ev[3][j].x, xB.x, pB3);
            pB3 = __builtin_fmaf(ev[3][j].y, xB.y, pB3);
            pB3 = __builtin_fmaf(ev[3][j].z, xB.z, pB3);
            pB3 = __builtin_fmaf(ev[3][j].w, xB.w, pB3);
        }
        // reduce over the 16 ds-lanes; A/B trees interleave on the pipe
        #pragma unroll
        for (int m = 1; m < 16; m <<= 1) {
            pA0 += __shfl_xor(pA0, m);
            pA1 += __shfl_xor(pA1, m);
            pA2 += __shfl_xor(pA2, m);
            pA3 += __shfl_xor(pA3, m);
            pB0 += __shfl_xor(pB0, m);
            pB1 += __shfl_xor(pB1, m);
            pB2 += __shfl_xor(pB2, m);
            pB3 += __shfl_xor(pB3, m);
        }
        if (ds == 0) {
            const float iqA = isq_lds[t];
            const float iqB = isq_lds[t + 1];
            float4 dA, dB;
            dA.x = (iqA + cb0) - 2.0f * pA0;
            dA.y = (iqA + cb1) - 2.0f * pA1;
            dA.z = (iqA + cb2) - 2.0f * pA2;
            dA.w = (iqA + cb3) - 2.0f * pA3;
            dB.x = (iqB + cb0) - 2.0f * pB0;
            dB.y = (iqB + cb1) - 2.0f * pB1;
            dB.z = (iqB + cb2) - 2.0f * pB2;
            dB.w = (iqB + cb3) - 2.0f * pB3;
            *(float4*)(dist_lds + t * DSTR + kbase) = dA;
            *(float4*)(dist_lds + (t + 1) * DSTR + kbase) = dB;
        }
    }
    __syncthreads();

    // ---- Phase D: per-token in-lane argmin (ascending k, strict < =>
    // exact numpy first-index). Lane t of wave 0 owns token t.
    if (wv == 0 && lane < TPB) {
        const int t = lane;
        const float* __restrict__ dr = dist_lds + t * DSTR;
        float f  = dr[0];
        int   fi = 0;
        #pragma unroll 8
        for (int kk = 1; kk < KK; ++kk) {
            const float v = dr[kk];
            const bool lt = v < f;
            f  = lt ? v  : f;
            fi = lt ? kk : fi;
        }
        out[NDQ + 1 + (size_t)(tok0 + t) * HH + h] = (float)fi;
        bi_lds[t] = fi;
        float ls = f;                    // min dist == ||q-x||^2 (~1e-6 rel)
        #pragma unroll
        for (int m = 1; m < TPB; m <<= 1) ls += __shfl_xor(ls, m);
        if (t == 0)
            partial[(size_t)h * NBX + blockIdx.x] = (double)ls;
    }
    __syncthreads();

    // ---- Phase E: q-row writes (8 rows/wave), gather from L2 codebook ----
    #pragma unroll
    for (int i = 0; i < TPB / 4; ++i) {
        const int row = wv * (TPB / 4) + i;
        const int kst = bi_lds[row];
        const float4 q4 = *(const float4*)(eh + (size_t)kst * HD + lane * 4);
        *(float4*)(out + (size_t)(tok0 + row) * DD + h * HD + lane * 4) = q4;
    }
}

__global__ void vq_finalize(const double* __restrict__ partial,
                            float* __restrict__ out)
{
    const int lane = threadIdx.x & 63;
    double s = 0.0;
    for (int i = 0; i < NPART / 64; ++i) s += partial[i * 64 + lane];
    #pragma unroll
    for (int m = 1; m < 64; m <<= 1) s += __shfl_xor(s, m);
    if (lane == 0) {
        const float mv = (float)(s / (double)NDQ);
        out[NDQ] = mv + 0.5f * mv;   // q_latent + 0.5*e_latent (equal values)
    }
}

extern "C" void kernel_launch(void* const* d_in, const int* in_sizes, int n_in,
                              void* d_out, int out_size, void* d_ws, size_t ws_size,
                              hipStream_t stream)
{
    const float* x   = (const float*)d_in[0];
    const float* emb = (const float*)d_in[1];
    float* out = (float*)d_out;
    double* partial = (double*)d_ws;                       // 4096 doubles
    float*  cbq     = (float*)((char*)d_ws + NPART * 8);   // 256 floats

    vq_cbq<<<1, dim3(256), 0, stream>>>(emb, cbq);
    vq_main<<<dim3(NBX, HH), dim3(256), 0, stream>>>(x, emb, cbq, out, partial);
    vq_finalize<<<1, dim3(64), 0, stream>>>(partial, out);
}

// Round 15
// 120.812 us; speedup vs baseline: 8.5960x; 1.2868x over previous
//
#include <hip/hip_runtime.h>

// Multi-head VQ: inputs (16,2048,1024) f32, embeddings (4,64,256) f32.
// Out flat f32: quantized_st[33554432] | loss[1] | indices[131072 as float].
// R15 = R14 with the 16-lane dot reduction moved from __shfl_xor
// (ds_bpermute, LDS pipe) to DPP adds (VALU pipe): xor1/xor2 quad_perm +
// row_ror:4/8 rotations — valid all-reduce for a commutative sum.
// Phase C LDS ops drop 40 -> 8 per 2-token iteration; LDS pipe was the
// serializing resource (R14: 33% VALUBusy, model ~124 us LDS-pipe time).
// lane=(kq=lane>>4, ds=lane&15) holds 4 codes x 16 dims of e in VGPRs.
// dist_lds + in-lane ascending-k scan keeps exact numpy first-index ties.
// isq byte-identical to R6. quantized_st written as q directly
// (|x+(q-x)-q| ~1e-6 << 1.26 thr); loss = min distance.

#define HH   4
#define KK   64
#define HD   256
#define DD   1024
#define NTOK 32768
#define NDQ  33554432ull
#define TPB  32            // tokens per block
#define NBX  (NTOK / TPB)  // 1024 blocks in x
#define NPART (NBX * HH)   // 4096 partials
#define XSTR 324           // floats per token row (16 slices * 20 + 4 skew)
#define DSTR 68            // padded float stride per-token dist row

template<int CTRL>
__device__ __forceinline__ float dpp_addstep(float v) {
    const int r = __builtin_amdgcn_update_dpp(
        0, __float_as_int(v), CTRL, 0xF, 0xF, true);
    return v + __int_as_float(r);
}
// Sum all-reduce within each 16-lane DPP row: xor1, xor2, ror4, ror8.
__device__ __forceinline__ float red16(float v) {
    v = dpp_addstep<0xB1>(v);    // quad_perm [1,0,3,2]  (xor 1)
    v = dpp_addstep<0x4E>(v);    // quad_perm [2,3,0,1]  (xor 2)
    v = dpp_addstep<0x124>(v);   // row_ror:4
    v = dpp_addstep<0x128>(v);   // row_ror:8
    return v;
}

__global__ void vq_cbq(const float* __restrict__ emb, float* __restrict__ cbq)
{
    const int t = threadIdx.x;               // one per (h,k)
    const float* e = emb + (size_t)t * HD;
    float s = 0.f;
    {
        #pragma clang fp contract(off)
        for (int d = 0; d < HD; ++d) {
            float p = e[d] * e[d];
            s = s + p;
        }
    }
    cbq[t] = s;
}

__global__ __launch_bounds__(256, 2) void vq_main(
    const float* __restrict__ x, const float* __restrict__ emb,
    const float* __restrict__ cbq, float* __restrict__ out,
    double* __restrict__ partial)
{
    __shared__ __align__(16) float x_lds[TPB * XSTR];      // 41472 B
    __shared__ __align__(16) float dist_lds[TPB * DSTR];   //  8704 B
    __shared__ float isq_lds[TPB];
    __shared__ int   bi_lds[TPB];

    const int h    = blockIdx.y;
    const int wv   = threadIdx.x >> 6;
    const int lane = threadIdx.x & 63;
    const int tok0 = blockIdx.x * TPB;

    const float* __restrict__ eh = emb + (size_t)h * (KK * HD);

    // ---- Phase A: lane holds 4 codes x 16 dims of e (16 float4) ----
    const int kq = lane >> 4;          // 0..3 code quad within wave slab
    const int ds = lane & 15;          // 0..15 dim slice (16 dims each)
    const int kbase = wv * 16 + kq * 4;
    float4 ev[4][4];
    #pragma unroll
    for (int m = 0; m < 4; ++m) {
        const float4* __restrict__ ep =
            (const float4*)(eh + (size_t)(kbase + m) * HD + ds * 16);
        #pragma unroll
        for (int j = 0; j < 4; ++j) ev[m][j] = ep[j];
    }
    const float cb0 = cbq[h * KK + kbase + 0];
    const float cb1 = cbq[h * KK + kbase + 1];
    const float cb2 = cbq[h * KK + kbase + 2];
    const float cb3 = cbq[h * KK + kbase + 3];

    // ---- Phase B: stage x-tile + isq (R6's exact pairwise order).
    // Wave wv handles tokens [wv*8, wv*8+8) only (exec-masked dedup).
    {
        const int tl = lane >> 1;
        const int hf = lane & 1;
        if ((tl >> 3) == wv) {
            const float* __restrict__ xr =
                x + (size_t)(tok0 + tl) * DD + h * HD + hf * 128;
            float r0=0.f,r1=0.f,r2=0.f,r3=0.f,r4=0.f,r5=0.f,r6=0.f,r7=0.f;
            #pragma unroll
            for (int cc = 0; cc < 8; ++cc) {
                const float4 v0 = ((const float4*)xr)[cc * 4 + 0];
                const float4 v1 = ((const float4*)xr)[cc * 4 + 1];
                const float4 v2 = ((const float4*)xr)[cc * 4 + 2];
                const float4 v3 = ((const float4*)xr)[cc * 4 + 3];
                float* dst = x_lds + tl * XSTR + (hf * 8 + cc) * 20;
                ((float4*)dst)[0] = v0; ((float4*)dst)[1] = v1;
                ((float4*)dst)[2] = v2; ((float4*)dst)[3] = v3;
                {
                    #pragma clang fp contract(off)
                    r0 = r0 + v0.x*v0.x;  r1 = r1 + v0.y*v0.y;
                    r2 = r2 + v0.z*v0.z;  r3 = r3 + v0.w*v0.w;
                    r4 = r4 + v1.x*v1.x;  r5 = r5 + v1.y*v1.y;
                    r6 = r6 + v1.z*v1.z;  r7 = r7 + v1.w*v1.w;
                    r0 = r0 + v2.x*v2.x;  r1 = r1 + v2.y*v2.y;
                    r2 = r2 + v2.z*v2.z;  r3 = r3 + v2.w*v2.w;
                    r4 = r4 + v3.x*v3.x;  r5 = r5 + v3.y*v3.y;
                    r6 = r6 + v3.z*v3.z;  r7 = r7 + v3.w*v3.w;
                }
            }
            const float hs = ((r0 + r1) + (r2 + r3)) + ((r4 + r5) + (r6 + r7));
            const float ho = __shfl_xor(hs, 1);
            if (hf == 0) isq_lds[tl] = hs + ho;  // halfA + halfB, numpy order
        }
    }
    __syncthreads();

    // ---- Phase C: dot loop, 2 tokens per iteration (independent chains),
    // DPP all-reduce over the 16 ds-lanes (VALU pipe, zero LDS ops).
    #pragma unroll 1
    for (int t = 0; t < TPB; t += 2) {
        const float4* __restrict__ xbA =
            (const float4*)(x_lds + t * XSTR + ds * 20);
        const float4* __restrict__ xbB =
            (const float4*)(x_lds + (t + 1) * XSTR + ds * 20);
        float pA0=0.f, pA1=0.f, pA2=0.f, pA3=0.f;
        float pB0=0.f, pB1=0.f, pB2=0.f, pB3=0.f;
        #pragma unroll
        for (int j = 0; j < 4; ++j) {
            const float4 xA = xbA[j];
            const float4 xB = xbB[j];
            pA0 = __builtin_fmaf(ev[0][j].x, xA.x, pA0);
            pA0 = __builtin_fmaf(ev[0][j].y, xA.y, pA0);
            pA0 = __builtin_fmaf(ev[0][j].z, xA.z, pA0);
            pA0 = __builtin_fmaf(ev[0][j].w, xA.w, pA0);
            pA1 = __builtin_fmaf(ev[1][j].x, xA.x, pA1);
            pA1 = __builtin_fmaf(ev[1][j].y, xA.y, pA1);
            pA1 = __builtin_fmaf(ev[1][j].z, xA.z, pA1);
            pA1 = __builtin_fmaf(ev[1][j].w, xA.w, pA1);
            pA2 = __builtin_fmaf(ev[2][j].x, xA.x, pA2);
            pA2 = __builtin_fmaf(ev[2][j].y, xA.y, pA2);
            pA2 = __builtin_fmaf(ev[2][j].z, xA.z, pA2);
            pA2 = __builtin_fmaf(ev[2][j].w, xA.w, pA2);
            pA3 = __builtin_fmaf(ev[3][j].x, xA.x, pA3);
            pA3 = __builtin_fmaf(ev[3][j].y, xA.y, pA3);
            pA3 = __builtin_fmaf(ev[3][j].z, xA.z, pA3);
            pA3 = __builtin_fmaf(ev[3][j].w, xA.w, pA3);
            pB0 = __builtin_fmaf(ev[0][j].x, xB.x, pB0);
            pB0 = __builtin_fmaf(ev[0][j].y, xB.y, pB0);
            pB0 = __builtin_fmaf(ev[0][j].z, xB.z, pB0);
            pB0 = __builtin_fmaf(ev[0][j].w, xB.w, pB0);
            pB1 = __builtin_fmaf(ev[1][j].x, xB.x, pB1);
            pB1 = __builtin_fmaf(ev[1][j].y, xB.y, pB1);
            pB1 = __builtin_fmaf(ev[1][j].z, xB.z, pB1);
            pB1 = __builtin_fmaf(ev[1][j].w, xB.w, pB1);
            pB2 = __builtin_fmaf(ev[2][j].x, xB.x, pB2);
            pB2 = __builtin_fmaf(ev[2][j].y, xB.y, pB2);
            pB2 = __builtin_fmaf(ev[2][j].z, xB.z, pB2);
            pB2 = __builtin_fmaf(ev[2][j].w, xB.w, pB2);
            pB3 = __builtin_fmaf(ev[3][j].x, xB.x, pB3);
            pB3 = __builtin_fmaf(ev[3][j].y, xB.y, pB3);
            pB3 = __builtin_fmaf(ev[3][j].z, xB.z, pB3);
            pB3 = __builtin_fmaf(ev[3][j].w, xB.w, pB3);
        }
        pA0 = red16(pA0);  pA1 = red16(pA1);
        pA2 = red16(pA2);  pA3 = red16(pA3);
        pB0 = red16(pB0);  pB1 = red16(pB1);
        pB2 = red16(pB2);  pB3 = red16(pB3);
        if (ds == 0) {
            const float iqA = isq_lds[t];
            const float iqB = isq_lds[t + 1];
            float4 dA, dB;
            dA.x = (iqA + cb0) - 2.0f * pA0;
            dA.y = (iqA + cb1) - 2.0f * pA1;
            dA.z = (iqA + cb2) - 2.0f * pA2;
            dA.w = (iqA + cb3) - 2.0f * pA3;
            dB.x = (iqB + cb0) - 2.0f * pB0;
            dB.y = (iqB + cb1) - 2.0f * pB1;
            dB.z = (iqB + cb2) - 2.0f * pB2;
            dB.w = (iqB + cb3) - 2.0f * pB3;
            *(float4*)(dist_lds + t * DSTR + kbase) = dA;
            *(float4*)(dist_lds + (t + 1) * DSTR + kbase) = dB;
        }
    }
    __syncthreads();

    // ---- Phase D: per-token in-lane argmin (ascending k, strict < =>
    // exact numpy first-index). Lane t of wave 0 owns token t.
    if (wv == 0 && lane < TPB) {
        const int t = lane;
        const float* __restrict__ dr = dist_lds + t * DSTR;
        float f  = dr[0];
        int   fi = 0;
        #pragma unroll 8
        for (int kk = 1; kk < KK; ++kk) {
            const float v = dr[kk];
            const bool lt = v < f;
            f  = lt ? v  : f;
            fi = lt ? kk : fi;
        }
        out[NDQ + 1 + (size_t)(tok0 + t) * HH + h] = (float)fi;
        bi_lds[t] = fi;
        float ls = f;                    // min dist == ||q-x||^2 (~1e-6 rel)
        #pragma unroll
        for (int m = 1; m < TPB; m <<= 1) ls += __shfl_xor(ls, m);
        if (t == 0)
            partial[(size_t)h * NBX + blockIdx.x] = (double)ls;
    }
    __syncthreads();

    // ---- Phase E: q-row writes (8 rows/wave), gather from L2 codebook ----
    #pragma unroll
    for (int i = 0; i < TPB / 4; ++i) {
        const int row = wv * (TPB / 4) + i;
        const int kst = bi_lds[row];
        const float4 q4 = *(const float4*)(eh + (size_t)kst * HD + lane * 4);
        *(float4*)(out + (size_t)(tok0 + row) * DD + h * HD + lane * 4) = q4;
    }
}

__global__ void vq_finalize(const double* __restrict__ partial,
                            float* __restrict__ out)
{
    const int lane = threadIdx.x & 63;
    double s = 0.0;
    for (int i = 0; i < NPART / 64; ++i) s += partial[i * 64 + lane];
    #pragma unroll
    for (int m = 1; m < 64; m <<= 1) s += __shfl_xor(s, m);
    if (lane == 0) {
        const float mv = (float)(s / (double)NDQ);
        out[NDQ] = mv + 0.5f * mv;   // q_latent + 0.5*e_latent (equal values)
    }
}

extern "C" void kernel_launch(void* const* d_in, const int* in_sizes, int n_in,
                              void* d_out, int out_size, void* d_ws, size_t ws_size,
                              hipStream_t stream)
{
    const float* x   = (const float*)d_in[0];
    const float* emb = (const float*)d_in[1];
    float* out = (float*)d_out;
    double* partial = (double*)d_ws;                       // 4096 doubles
    float*  cbq     = (float*)((char*)d_ws + NPART * 8);   // 256 floats

    vq_cbq<<<1, dim3(256), 0, stream>>>(emb, cbq);
    vq_main<<<dim3(NBX, HH), dim3(256), 0, stream>>>(x, emb, cbq, out, partial);
    vq_finalize<<<1, dim3(64), 0, stream>>>(partial, out);
}